// Round 13
// baseline (337923.413 us; speedup 1.0000x reference)
//
#include <hip/hip_runtime.h>
#include <math.h>

#define T_LEN 256
#define H_DIM 1024
#define V_DIM 50257
#define G3    3072   // 3*H
#define NBLK  128u   // grid size of the recurrence kernels
#define NXCD  8

typedef __attribute__((ext_vector_type(8))) short bf16x8;
typedef __attribute__((ext_vector_type(4))) float f32x4;
typedef __attribute__((ext_vector_type(4))) double f64x4;
typedef __attribute__((ext_vector_type(4))) unsigned int u32x4;

// ---------------- helpers ----------------
__device__ __forceinline__ double wred_sum_d(double v) {
#pragma unroll
  for (int off = 32; off > 0; off >>= 1) v += __shfl_down(v, off);
  return v;
}
__device__ __forceinline__ double wred_max_d(double v) {
#pragma unroll
  for (int off = 32; off > 0; off >>= 1) v = fmax(v, __shfl_down(v, off));
  return v;
}
__device__ __forceinline__ double sigm_d(double x) { return 1.0 / (1.0 + exp(-x)); }
__device__ __forceinline__ unsigned short f2bf(float f) {
  unsigned int u = __float_as_uint(f);
  return (unsigned short)((u + 0x7fffu + ((u >> 16) & 1u)) >> 16);
}

// ---------------- tagged-mailbox primitives ----------------
// 16B {value, epoch} slots, packed (r9 layout — r12's 64B padding regressed).
// GLOBAL flavor (sc0 sc1): coherent device-wide at the Infinity-Cache point
// (~4.5us producer->all-consumers, measured r5/r6/r9).
// LOCAL flavor (sc0 only): coherent at the XCD's own L2 — valid ONLY when all
// parties are on the same XCD (discovered via HW_REG_XCC_ID) — ~0.1-0.5us hop.
// Poll guards bound any broken exchange to a wrong answer, never a hang.
__device__ __forceinline__ u32x4 pack2(double v, double tag) {
  unsigned long long uv = __double_as_longlong(v);
  unsigned long long ut = __double_as_longlong(tag);
  u32x4 d;
  d.x = (unsigned)uv; d.y = (unsigned)(uv >> 32);
  d.z = (unsigned)ut; d.w = (unsigned)(ut >> 32);
  return d;
}
__device__ __forceinline__ double val_of(u32x4 r) {
  return __longlong_as_double(((unsigned long long)r.y << 32) | r.x);
}
__device__ __forceinline__ double tag_of(u32x4 r) {
  return __longlong_as_double(((unsigned long long)r.w << 32) | r.z);
}
// -------- global (device) scope --------
__device__ __forceinline__ void tstore(double* p, double v, double tag) {
  u32x4 d = pack2(v, tag);
  asm volatile("global_store_dwordx4 %0, %1, off sc0 sc1"
               :: "v"(p), "v"(d) : "memory");
}
__device__ __forceinline__ u32x4 tload1(const double* p) {
  u32x4 r;
  asm volatile("global_load_dwordx4 %0, %1, off sc0 sc1\n\t"
               "s_waitcnt vmcnt(0)"
               : "=&v"(r) : "v"(p) : "memory");
  return r;
}
__device__ __forceinline__ void tload4(const double* p, u32x4& a, u32x4& b,
                                       u32x4& c, u32x4& d) {
  asm volatile("global_load_dwordx4 %0, %4, off sc0 sc1\n\t"
               "global_load_dwordx4 %1, %4, off offset:16 sc0 sc1\n\t"
               "global_load_dwordx4 %2, %4, off offset:32 sc0 sc1\n\t"
               "global_load_dwordx4 %3, %4, off offset:48 sc0 sc1\n\t"
               "s_waitcnt vmcnt(0)"
               : "=&v"(a), "=&v"(b), "=&v"(c), "=&v"(d)
               : "v"(p) : "memory");
}
__device__ __forceinline__ void poll4(const double* p, double want, double* dst) {
  u32x4 a, b, c, d;
  int guard = 0;
  for (;;) {
    tload4(p, a, b, c, d);
    if (tag_of(a) == want && tag_of(b) == want &&
        tag_of(c) == want && tag_of(d) == want) break;
    __builtin_amdgcn_s_sleep(1);
    if (++guard > (1 << 13)) break;   // fail-safe
  }
  dst[0] = val_of(a); dst[1] = val_of(b); dst[2] = val_of(c); dst[3] = val_of(d);
}
__device__ __forceinline__ double poll1(const double* p, double want) {
  int guard = 0;
  for (;;) {
    u32x4 r = tload1(p);
    if (tag_of(r) == want) return val_of(r);
    __builtin_amdgcn_s_sleep(1);
    if (++guard > (1 << 13)) return val_of(r);   // fail-safe
  }
}
// -------- XCD-local (L2) scope --------
__device__ __forceinline__ void tstoreL(double* p, double v, double tag) {
  u32x4 d = pack2(v, tag);
  asm volatile("global_store_dwordx4 %0, %1, off sc0"
               :: "v"(p), "v"(d) : "memory");
}
__device__ __forceinline__ u32x4 tload1L(const double* p) {
  u32x4 r;
  asm volatile("global_load_dwordx4 %0, %1, off sc0\n\t"
               "s_waitcnt vmcnt(0)"
               : "=&v"(r) : "v"(p) : "memory");
  return r;
}
__device__ __forceinline__ void tload4L(const double* p, u32x4& a, u32x4& b,
                                        u32x4& c, u32x4& d) {
  asm volatile("global_load_dwordx4 %0, %4, off sc0\n\t"
               "global_load_dwordx4 %1, %4, off offset:16 sc0\n\t"
               "global_load_dwordx4 %2, %4, off offset:32 sc0\n\t"
               "global_load_dwordx4 %3, %4, off offset:48 sc0\n\t"
               "s_waitcnt vmcnt(0)"
               : "=&v"(a), "=&v"(b), "=&v"(c), "=&v"(d)
               : "v"(p) : "memory");
}
__device__ __forceinline__ void poll4L(const double* p, double want, double* dst) {
  u32x4 a, b, c, d;
  int guard = 0;
  for (;;) {
    tload4L(p, a, b, c, d);
    if (tag_of(a) == want && tag_of(b) == want &&
        tag_of(c) == want && tag_of(d) == want) break;
    __builtin_amdgcn_s_sleep(1);
    if (++guard > (1 << 13)) break;   // fail-safe
  }
  dst[0] = val_of(a); dst[1] = val_of(b); dst[2] = val_of(c); dst[3] = val_of(d);
}
__device__ __forceinline__ double poll1L(const double* p, double want) {
  int guard = 0;
  for (;;) {
    u32x4 r = tload1L(p);
    if (tag_of(r) == want) return val_of(r);
    __builtin_amdgcn_s_sleep(1);
    if (++guard > (1 << 13)) return val_of(r);   // fail-safe
  }
}

// ---------------- tiny prep kernels ----------------
__global__ void gather_emb_kernel(const int* __restrict__ target,
                                  const float* __restrict__ emb_dec,
                                  float* __restrict__ emb) {
  int t = blockIdx.x;
  int tok = (t == 0) ? 1 : target[t - 1];          // SOS=1, teacher forcing
  const float4* s = (const float4*)(emb_dec + (size_t)tok * H_DIM);
  float4* d = (float4*)(emb + (size_t)t * H_DIM);
  d[threadIdx.x] = s[threadIdx.x];
}

// init all tags/counters -> deterministic replays
__global__ void init_tags_kernel(double* __restrict__ hT,
                                 double* __restrict__ sM,
                                 double* __restrict__ cM,
                                 double* __restrict__ ready,
                                 unsigned* __restrict__ regs) {
  int tid = threadIdx.x;
  for (int i = tid; i < 2 * H_DIM; i += 256) {       // hT (2 parities)
    hT[2 * i] = 0.0;
    hT[2 * i + 1] = (i < H_DIM) ? 0.0 : -1.0;
  }
  for (int i = tid; i < NXCD * 256; i += 256) {      // sM
    sM[2 * i] = 0.0; sM[2 * i + 1] = -1.0;
  }
  for (int i = tid; i < NXCD * 1024; i += 256) {     // cM
    cM[2 * i] = 0.0; cM[2 * i + 1] = -1.0;
  }
  if (tid == 0) { ready[0] = 0.0; ready[1] = -1.0; }
  if (tid < 16) regs[tid] = 0u;                      // cnt8 + tot
}

__global__ void cvt_bf16_kernel(const double* __restrict__ src,
                                unsigned short* __restrict__ dst) {
  int i = blockIdx.x * blockDim.x + threadIdx.x;   // one f64x4 each, 65536 total
  f64x4 v = ((const f64x4*)src)[i];
  ushort4 o;
  o.x = f2bf((float)v.x); o.y = f2bf((float)v.y);
  o.z = f2bf((float)v.z); o.w = f2bf((float)v.w);
  *(ushort4*)&dst[i * 4] = o;
}

// ---------------- generic f64-accum GEMM: C[m,n] = bias[n] + dot(A[m,:],B[n,:]) --
template <typename TA, typename TB>
__global__ __launch_bounds__(256) void gemm_nt_f64acc(
    const TA* __restrict__ A, int lda,
    const TB* __restrict__ B, int ldb,
    const float* __restrict__ bias,
    double* __restrict__ C, int ldc, int K) {
  __shared__ double As[32][65];
  __shared__ double Bs[32][65];
  const int tid = threadIdx.x;
  const int tx = tid & 15, ty = tid >> 4;
  const int m0 = blockIdx.y * 64, n0 = blockIdx.x * 64;
  double acc[4][4];
#pragma unroll
  for (int i = 0; i < 4; ++i)
#pragma unroll
    for (int j = 0; j < 4; ++j) acc[i][j] = 0.0;

  for (int k0 = 0; k0 < K; k0 += 32) {
#pragma unroll
    for (int q = 0; q < 8; ++q) {
      int idx = q * 256 + tid;          // 0..2047
      int row = idx >> 5;               // 0..63
      int col = idx & 31;               // 0..31
      As[col][row] = (double)A[(size_t)(m0 + row) * lda + k0 + col];
      Bs[col][row] = (double)B[(size_t)(n0 + row) * ldb + k0 + col];
    }
    __syncthreads();
#pragma unroll
    for (int kk = 0; kk < 32; ++kk) {
      double a[4], b[4];
#pragma unroll
      for (int i = 0; i < 4; ++i) a[i] = As[kk][ty * 4 + i];
#pragma unroll
      for (int j = 0; j < 4; ++j) b[j] = Bs[kk][tx * 4 + j];
#pragma unroll
      for (int i = 0; i < 4; ++i)
#pragma unroll
        for (int j = 0; j < 4; ++j) acc[i][j] += a[i] * b[j];
    }
    __syncthreads();
  }
#pragma unroll
  for (int j = 0; j < 4; ++j) {
    double bj = bias ? (double)bias[n0 + tx * 4 + j] : 0.0;
#pragma unroll
    for (int i = 0; i < 4; ++i)
      C[(size_t)(m0 + ty * 4 + i) * ldc + n0 + tx * 4 + j] = acc[i][j] + bj;
  }
}

// ---------------- encoder: 256 GRU steps, tagged-dataflow exchange (r9) ---------
__global__ __launch_bounds__(256) void enc_kernel(
    const double* __restrict__ gxe,     // [256][3072] input-side gates (incl bih)
    const float* __restrict__ Whh,      // [3072][1024]
    const float* __restrict__ bhh,      // [3072]
    double* __restrict__ hT,            // [2][1024] tagged (2 doubles/elem)
    double* __restrict__ enc_outs) {    // [256][1024]
  __shared__ __align__(32) double hs[H_DIM];
  const int tid = threadIdx.x;
  const int lane = tid & 63, wave = tid >> 6;
  const int gwave = blockIdx.x * 4 + wave;   // 0..511

  for (int t = 0; t < T_LEN; ++t) {
    poll4(&hT[2 * ((size_t)(t & 1) * H_DIM + tid * 4)], (double)t, &hs[tid * 4]);
    __syncthreads();

#pragma unroll
    for (int jj = 0; jj < 2; ++jj) {
      int j = gwave * 2 + jj;   // 0..1023
      const float4* wr = (const float4*)(Whh + (size_t)j * H_DIM);
      const float4* wz = (const float4*)(Whh + (size_t)(j + 1024) * H_DIM);
      const float4* wn = (const float4*)(Whh + (size_t)(j + 2048) * H_DIM);
      const f64x4* h4 = (const f64x4*)hs;
      double ar = 0.0, az = 0.0, an = 0.0;
#pragma unroll
      for (int i = 0; i < 4; ++i) {
        int k = lane + 64 * i;
        f64x4 hv = h4[k];
        float4 r4 = wr[k], z4 = wz[k], n4 = wn[k];
        ar += hv.x * (double)r4.x + hv.y * (double)r4.y + hv.z * (double)r4.z + hv.w * (double)r4.w;
        az += hv.x * (double)z4.x + hv.y * (double)z4.y + hv.z * (double)z4.z + hv.w * (double)z4.w;
        an += hv.x * (double)n4.x + hv.y * (double)n4.y + hv.z * (double)n4.z + hv.w * (double)n4.w;
      }
      ar = wred_sum_d(ar); az = wred_sum_d(az); an = wred_sum_d(an);
      if (lane == 0) {
        const double* gx = gxe + (size_t)t * G3;
        double r = sigm_d(gx[j] + ar + (double)bhh[j]);
        double z = sigm_d(gx[1024 + j] + az + (double)bhh[1024 + j]);
        double n = tanh(gx[2048 + j] + r * (an + (double)bhh[2048 + j]));
        double hnew = (1.0 - z) * n + z * hs[j];
        tstore(&hT[2 * ((size_t)((t + 1) & 1) * H_DIM + j)], hnew, (double)(t + 1));
        enc_outs[(size_t)t * H_DIM + j] = hnew;   // post-kernel consumer
      }
    }
    __syncthreads();   // protect hs before next step's poll-fill
  }
}

// ---------------- decoder: 1 global hop + 2 XCD-local hops per step -------------
// s and comb are computed REDUNDANTLY PER XCD (bit-identical values across XCDs:
// each dot is one wave with a fixed order), exchanged via sc0-only L2-local
// mailboxes. Only h crosses XCDs. Block->XCD discovered via HW_REG_XCC_ID +
// atomic registration (handles any distribution; ranks vary per run but values
// don't -> output replay-deterministic). Race-freedom: same dependency-cycle
// argument as r9, applied per mailbox.
__global__ __launch_bounds__(256) void dec_kernel(
    const double* __restrict__ s_emb,   // [256][256]  emb@attnW_e.T + attn_b
    const double* __restrict__ cp,      // [256][1024] emb@combW_e.T + comb_b
    const double* __restrict__ M1T,     // [1024][256] combW_c @ enc_outs.T
    const float* __restrict__ attn_W,   // [256][2048]
    const float* __restrict__ Wih,      // dec [3072][1024]
    const float* __restrict__ Whh,      // dec [3072][1024]
    const float* __restrict__ bih,      // [3072]
    const float* __restrict__ bhh,      // [3072]
    double* __restrict__ hD,            // [1024] global tagged (tag 256+t -> 257+t)
    double* __restrict__ sM,            // [8][256] XCD-local tagged (tag t+1)
    double* __restrict__ cM,            // [8][1024] XCD-local tagged (tag t+1)
    double* __restrict__ ready,         // registration ready slot
    unsigned* __restrict__ regs,        // [0..7]=cnt per xcd, [8]=tot
    double* __restrict__ h_dec) {       // [256][1024]
  __shared__ __align__(32) double hs[H_DIM];
  __shared__ __align__(32) double cs[H_DIM];
  __shared__ __align__(32) double aw[T_LEN];
  __shared__ double rmax[4], rsum[4];
  __shared__ double whh_p[4][2][3];
  __shared__ unsigned sh_x, sh_r, sh_c;
  const int tid = threadIdx.x;
  const int lane = tid & 63, wave = tid >> 6;
  const int gwave = blockIdx.x * 4 + wave;   // 0..511

  // ---- one-time registration ----
  if (tid == 0) {
    unsigned x;
    asm volatile("s_getreg_b32 %0, hwreg(HW_REG_XCC_ID)" : "=s"(x));
    x &= (NXCD - 1);
    unsigned r = __hip_atomic_fetch_add(&regs[x], 1u, __ATOMIC_RELAXED,
                                        __HIP_MEMORY_SCOPE_AGENT);
    unsigned o = __hip_atomic_fetch_add(&regs[8], 1u, __ATOMIC_RELAXED,
                                        __HIP_MEMORY_SCOPE_AGENT);
    if (o == NBLK - 1) tstore(ready, 0.0, 777.0);
    else (void)poll1(ready, 777.0);
    sh_x = x; sh_r = r;
    sh_c = __hip_atomic_load(&regs[x], __ATOMIC_RELAXED, __HIP_MEMORY_SCOPE_AGENT);
  }
  __syncthreads();
  const unsigned xcd = sh_x;
  const int rank = (int)sh_r, cnt = (int)(sh_c ? sh_c : 1);
  double* sMx = sM + (size_t)xcd * 256 * 2;
  double* cMx = cM + (size_t)xcd * 1024 * 2;

  for (int t = 0; t < T_LEN; ++t) {
    // ---- phase 1: global h poll; redundant s-dots (per-XCD split); Whh dots ----
    poll4(&hD[2 * (tid * 4)], (double)(256 + t), &hs[tid * 4]);
    __syncthreads();

    for (int i = wave; ; i += 4) {       // s logit j = rank + i*cnt (wave-uniform)
      int j = rank + i * cnt;
      if (j >= 256) break;
      const float4* w4 = (const float4*)(attn_W + (size_t)j * 2048 + 1024);
      const f64x4* h4 = (const f64x4*)hs;
      double acc = 0.0;
#pragma unroll
      for (int q = 0; q < 4; ++q) {
        int k = lane + 64 * q;
        float4 wv = w4[k]; f64x4 hv = h4[k];
        acc += (double)wv.x * hv.x + (double)wv.y * hv.y +
               (double)wv.z * hv.z + (double)wv.w * hv.w;
      }
      acc = wred_sum_d(acc);
      if (lane == 0)
        tstoreL(&sMx[2 * j], s_emb[(size_t)t * T_LEN + j] + acc, (double)(t + 1));
    }
#pragma unroll
    for (int jj = 0; jj < 2; ++jj) {
      int j = gwave * 2 + jj;
      const float4* whr = (const float4*)(Whh + (size_t)j * H_DIM);
      const float4* whz = (const float4*)(Whh + (size_t)(j + 1024) * H_DIM);
      const float4* whn = (const float4*)(Whh + (size_t)(j + 2048) * H_DIM);
      const f64x4* h4 = (const f64x4*)hs;
      double ahr = 0.0, ahz = 0.0, ahn = 0.0;
#pragma unroll
      for (int i = 0; i < 4; ++i) {
        int k = lane + 64 * i;
        f64x4 hv = h4[k];
        float4 t3 = whr[k], t4 = whz[k], t5 = whn[k];
        ahr += hv.x * (double)t3.x + hv.y * (double)t3.y + hv.z * (double)t3.z + hv.w * (double)t3.w;
        ahz += hv.x * (double)t4.x + hv.y * (double)t4.y + hv.z * (double)t4.z + hv.w * (double)t4.w;
        ahn += hv.x * (double)t5.x + hv.y * (double)t5.y + hv.z * (double)t5.z + hv.w * (double)t5.w;
      }
      ahr = wred_sum_d(ahr); ahz = wred_sum_d(ahz); ahn = wred_sum_d(ahn);
      if (lane == 0) {
        whh_p[wave][jj][0] = ahr + (double)bhh[j];
        whh_p[wave][jj][1] = ahz + (double)bhh[1024 + j];
        whh_p[wave][jj][2] = ahn + (double)bhh[2048 + j];
      }
    }

    // ---- phase 2: XCD-local s poll; softmax; redundant comb (per-XCD split) ----
    {
      double sv = poll1L(&sMx[2 * tid], (double)(t + 1));   // tid < 256 exactly
      double m = wred_max_d(sv);
      if (lane == 0) rmax[wave] = m;
      __syncthreads();
      double mx = fmax(fmax(rmax[0], rmax[1]), fmax(rmax[2], rmax[3]));
      double e = exp(sv - mx);
      double ssum = wred_sum_d(e);
      if (lane == 0) rsum[wave] = ssum;
      __syncthreads();
      double inv = 1.0 / (rsum[0] + rsum[1] + rsum[2] + rsum[3]);
      aw[tid] = e * inv;
      __syncthreads();
    }
    for (int i = wave; ; i += 4) {       // comb channel c = rank + i*cnt
      int c = rank + i * cnt;
      if (c >= 1024) break;
      f64x4 mv = ((const f64x4*)(M1T + (size_t)c * T_LEN))[lane];
      f64x4 av = ((const f64x4*)aw)[lane];
      double acc = mv.x * av.x + mv.y * av.y + mv.z * av.z + mv.w * av.w;
      acc = wred_sum_d(acc);
      if (lane == 0) {
        double v = cp[(size_t)t * H_DIM + c] + acc;
        tstoreL(&cMx[2 * c], v > 0.0 ? v : 0.0, (double)(t + 1));
      }
    }

    // ---- phase 3: XCD-local comb poll; Wih dots + gates; global h publish ----
    poll4L(&cMx[2 * (tid * 4)], (double)(t + 1), &cs[tid * 4]);
    __syncthreads();
#pragma unroll
    for (int jj = 0; jj < 2; ++jj) {
      int j = gwave * 2 + jj;
      const float4* wir = (const float4*)(Wih + (size_t)j * H_DIM);
      const float4* wiz = (const float4*)(Wih + (size_t)(j + 1024) * H_DIM);
      const float4* win = (const float4*)(Wih + (size_t)(j + 2048) * H_DIM);
      const f64x4* c4 = (const f64x4*)cs;
      double air = 0.0, aiz = 0.0, ain = 0.0;
#pragma unroll
      for (int i = 0; i < 4; ++i) {
        int k = lane + 64 * i;
        f64x4 cv = c4[k];
        float4 t0 = wir[k], t1 = wiz[k], t2 = win[k];
        air += cv.x * (double)t0.x + cv.y * (double)t0.y + cv.z * (double)t0.z + cv.w * (double)t0.w;
        aiz += cv.x * (double)t1.x + cv.y * (double)t1.y + cv.z * (double)t1.z + cv.w * (double)t1.w;
        ain += cv.x * (double)t2.x + cv.y * (double)t2.y + cv.z * (double)t2.z + cv.w * (double)t2.w;
      }
      air = wred_sum_d(air); aiz = wred_sum_d(aiz); ain = wred_sum_d(ain);
      if (lane == 0) {
        double r = sigm_d(air + (double)bih[j] + whh_p[wave][jj][0]);
        double z = sigm_d(aiz + (double)bih[1024 + j] + whh_p[wave][jj][1]);
        double n = tanh(ain + (double)bih[2048 + j] + r * whh_p[wave][jj][2]);
        double hnew = (1.0 - z) * n + z * hs[j];
        tstore(&hD[2 * j], hnew, (double)(257 + t));
        h_dec[(size_t)t * H_DIM + j] = hnew;   // post-kernel consumer
      }
    }
    __syncthreads();   // protect hs/cs/aw/whh_p before next step's poll-fill
  }
}

// ---------------- output GEMM: C[256,50257] = Abf @ out_W.T + out_b (bf16 MFMA) --
__global__ __launch_bounds__(256) void out_gemm_kernel(
    const unsigned short* __restrict__ Abf,  // [256][1024] bf16
    const float* __restrict__ Bw,            // [50257][1024] f32 (converted inline)
    const float* __restrict__ bias,          // [50257]
    float* __restrict__ C) {                 // [256][50257]
  __shared__ unsigned short As[256][40];
  __shared__ unsigned short Bs[64][40];
  const int tid = threadIdx.x;
  const int lane = tid & 63, wave = tid >> 6;
  const int n0 = blockIdx.x * 64;
  f32x4 acc[4][4];
#pragma unroll
  for (int i = 0; i < 4; ++i)
#pragma unroll
    for (int j = 0; j < 4; ++j) acc[i][j] = (f32x4){0.f, 0.f, 0.f, 0.f};

  for (int k0 = 0; k0 < 1024; k0 += 32) {
#pragma unroll
    for (int q = 0; q < 4; ++q) {               // stage A: [256][32] bf16
      int idx = (tid + q * 256) * 8;
      int m = idx >> 5, k = idx & 31;
      uint4 v = *(const uint4*)&Abf[(size_t)m * H_DIM + k0 + k];
      *(uint4*)&As[m][k] = v;
    }
#pragma unroll
    for (int q = 0; q < 2; ++q) {               // stage B: [64][32] f32 -> bf16
      int idx = (tid + q * 256) * 4;
      int r = idx >> 5, c = idx & 31;
      int n = n0 + r;
      float4 v = make_float4(0.f, 0.f, 0.f, 0.f);
      if (n < V_DIM) v = *(const float4*)&Bw[(size_t)n * H_DIM + k0 + c];
      ushort4 o;
      o.x = f2bf(v.x); o.y = f2bf(v.y); o.z = f2bf(v.z); o.w = f2bf(v.w);
      *(ushort4*)&Bs[r][c] = o;
    }
    __syncthreads();
    bf16x8 a[4], b[4];
#pragma unroll
    for (int i = 0; i < 4; ++i)
      a[i] = *(const bf16x8*)&As[wave * 64 + i * 16 + (lane & 15)][(lane >> 4) * 8];
#pragma unroll
    for (int j = 0; j < 4; ++j)
      b[j] = *(const bf16x8*)&Bs[j * 16 + (lane & 15)][(lane >> 4) * 8];
#pragma unroll
    for (int i = 0; i < 4; ++i)
#pragma unroll
      for (int j = 0; j < 4; ++j)
        acc[i][j] = __builtin_amdgcn_mfma_f32_16x16x32_bf16(a[i], b[j], acc[i][j], 0, 0, 0);
    __syncthreads();
  }
  const int col = lane & 15, rgrp = lane >> 4;
#pragma unroll
  for (int j = 0; j < 4; ++j) {
    int n = n0 + j * 16 + col;
    if (n >= V_DIM) continue;
    float bv = bias[n];
#pragma unroll
    for (int i = 0; i < 4; ++i) {
      int mbase = wave * 64 + i * 16 + rgrp * 4;
#pragma unroll
      for (int r = 0; r < 4; ++r)
        C[(size_t)(mbase + r) * V_DIM + n] = acc[i][j][r] + bv;
    }
  }
}

// ---------------- in-place row log_softmax over V (f64 sum) ----------------
__global__ __launch_bounds__(1024) void logsoftmax_kernel(float* __restrict__ x) {
  const int row = blockIdx.x;
  float* p = x + (size_t)row * V_DIM;
  const int tid = threadIdx.x;
  __shared__ float redf[16];
  __shared__ double redd[16];
  float mx = -3.4e38f;
  for (int i = tid; i < V_DIM; i += 1024) mx = fmaxf(mx, p[i]);
#pragma unroll
  for (int off = 32; off > 0; off >>= 1) mx = fmaxf(mx, __shfl_down(mx, off));
  if ((tid & 63) == 0) redf[tid >> 6] = mx;
  __syncthreads();
  mx = redf[0];
#pragma unroll
  for (int i = 1; i < 16; ++i) mx = fmaxf(mx, redf[i]);
  __syncthreads();
  double s = 0.0;
  for (int i = tid; i < V_DIM; i += 1024) s += exp((double)p[i] - (double)mx);
  s = wred_sum_d(s);
  if ((tid & 63) == 0) redd[tid >> 6] = s;
  __syncthreads();
  s = 0.0;
#pragma unroll
  for (int i = 0; i < 16; ++i) s += redd[i];
  double lse = (double)mx + log(s);
  for (int i = tid; i < V_DIM; i += 1024) p[i] = (float)((double)p[i] - lse);
}

// ---------------- launch ----------------
extern "C" void kernel_launch(void* const* d_in, const int* in_sizes, int n_in,
                              void* d_out, int out_size, void* d_ws, size_t ws_size,
                              hipStream_t stream) {
  const float* input_seq = (const float*)d_in[0];
  const int*   target    = (const int*)d_in[1];
  const float* emb_dec   = (const float*)d_in[2];
  const float* enc_Wih   = (const float*)d_in[3];
  const float* enc_Whh   = (const float*)d_in[4];
  const float* enc_bih   = (const float*)d_in[5];
  const float* enc_bhh   = (const float*)d_in[6];
  const float* attn_W    = (const float*)d_in[7];
  const float* attn_b    = (const float*)d_in[8];
  const float* comb_W    = (const float*)d_in[9];
  const float* comb_b    = (const float*)d_in[10];
  const float* dec_Wih   = (const float*)d_in[11];
  const float* dec_Whh   = (const float*)d_in[12];
  const float* dec_bih   = (const float*)d_in[13];
  const float* dec_bhh   = (const float*)d_in[14];
  const float* out_W     = (const float*)d_in[15];
  const float* out_b     = (const float*)d_in[16];
  float* out = (float*)d_out;

  // f64 scratch that dies before out_gemm lives inside d_out (51.5 MB total).
  double* od = (double*)d_out;
  double* gxe      = od;                     // 256*3072  (dead after enc)
  double* s_emb    = gxe + 256 * 3072;       // 256*256   (dead after dec)
  double* cp       = s_emb + 256 * 256;      // 256*1024  (dead after dec)
  double* enc_outs = cp + 256 * 1024;        // 256*1024  (dead after M1T)
  double* M1T      = enc_outs + 256 * 1024;  // 1024*256  (dead after dec)
  double* h_dec    = M1T + 1024 * 256;       // 256*1024  (dead after cvt)
  // persistent-through-out_gemm scratch in d_ws (tagged elems = 2 doubles)
  double* hT    = (double*)d_ws;             // [2][1024] tagged h
  double* sM    = hT + 2 * 2 * H_DIM;        // [8][256] XCD-local s
  double* cM    = sM + 2 * NXCD * 256;       // [8][1024] XCD-local comb
  double* ready = cM + 2 * NXCD * 1024;      // 2 doubles (16B aligned)
  unsigned* regs = (unsigned*)(ready + 2);   // cnt8[8] + tot (16 u32 reserved)
  float*  emb = (float*)(ready + 2 + 8);                         // 256*1024 f32
  unsigned short* hdec_bf = (unsigned short*)(emb + 256 * 1024); // 256*1024 bf16

  // prep (re-inits all tags/counters -> deterministic replays)
  gather_emb_kernel<<<256, 256, 0, stream>>>(target, emb_dec, emb);
  init_tags_kernel<<<1, 256, 0, stream>>>(hT, sM, cM, ready, regs);

  // f64-accum pre-GEMMs
  gemm_nt_f64acc<float, float><<<dim3(48, 4), 256, 0, stream>>>(
      input_seq, 1024, enc_Wih, 1024, enc_bih, gxe, 3072, 1024);
  gemm_nt_f64acc<float, float><<<dim3(4, 4), 256, 0, stream>>>(
      emb, 1024, attn_W, 2048, attn_b, s_emb, 256, 1024);
  gemm_nt_f64acc<float, float><<<dim3(16, 4), 256, 0, stream>>>(
      emb, 1024, comb_W, 2048, comb_b, cp, 1024, 1024);

  // encoder recurrence (leaves h tag=256 in hT slots [0..1023])
  enc_kernel<<<NBLK, 256, 0, stream>>>(gxe, enc_Whh, enc_bhh, hT, enc_outs);

  // M1T = comb_W[:, H:] @ enc_outs.T -> [1024][256]
  gemm_nt_f64acc<float, double><<<dim3(4, 16), 256, 0, stream>>>(
      comb_W + 1024, 2048, enc_outs, 1024, nullptr, M1T, 256, 1024);

  // decoder recurrence (1 global hop + 2 XCD-local hops per step)
  dec_kernel<<<NBLK, 256, 0, stream>>>(s_emb, cp, M1T, attn_W, dec_Wih, dec_Whh,
                                       dec_bih, dec_bhh, hT, sM, cM, ready, regs,
                                       h_dec);

  // output projection + log_softmax (overwrites all of d_out)
  cvt_bf16_kernel<<<256, 256, 0, stream>>>(h_dec, hdec_bf);
  out_gemm_kernel<<<786, 256, 0, stream>>>(hdec_bf, out_W, out_b, out);
  logsoftmax_kernel<<<256, 1024, 0, stream>>>(out);
}

// Round 14
// 4740.239 us; speedup vs baseline: 71.2883x; 71.2883x over previous
//
#include <hip/hip_runtime.h>
#include <math.h>

#define T_LEN 256
#define H_DIM 1024
#define V_DIM 50257
#define G3    3072   // 3*H
#define NBLK  128u   // grid size of the recurrence kernels

typedef __attribute__((ext_vector_type(8))) short bf16x8;
typedef __attribute__((ext_vector_type(4))) float f32x4;
typedef __attribute__((ext_vector_type(4))) double f64x4;
typedef __attribute__((ext_vector_type(4))) unsigned int u32x4;

// ---------------- helpers ----------------
__device__ __forceinline__ double wred_sum_d(double v) {
#pragma unroll
  for (int off = 32; off > 0; off >>= 1) v += __shfl_down(v, off);
  return v;
}
__device__ __forceinline__ double wred_max_d(double v) {
#pragma unroll
  for (int off = 32; off > 0; off >>= 1) v = fmax(v, __shfl_down(v, off));
  return v;
}
__device__ __forceinline__ double sigm_d(double x) { return 1.0 / (1.0 + exp(-x)); }
__device__ __forceinline__ unsigned short f2bf(float f) {
  unsigned int u = __float_as_uint(f);
  return (unsigned short)((u + 0x7fffu + ((u >> 16) & 1u)) >> 16);
}

// ---------------- tagged-mailbox dataflow primitives (r9 layout) ----------------
// 16B {value, epoch} packed slots, device-coherent (sc0 sc1) single-transaction
// publish; consumers poll the data itself. r12 (64B slots, 64 blocks) and r13
// (sc0-only XCD-local) both REGRESSED -- this r9 protocol is the best measured.
// Poll guard bounds a broken exchange to a wrong answer, never a hang.
__device__ __forceinline__ u32x4 pack2(double v, double tag) {
  unsigned long long uv = __double_as_longlong(v);
  unsigned long long ut = __double_as_longlong(tag);
  u32x4 d;
  d.x = (unsigned)uv; d.y = (unsigned)(uv >> 32);
  d.z = (unsigned)ut; d.w = (unsigned)(ut >> 32);
  return d;
}
__device__ __forceinline__ double val_of(u32x4 r) {
  return __longlong_as_double(((unsigned long long)r.y << 32) | r.x);
}
__device__ __forceinline__ double tag_of(u32x4 r) {
  return __longlong_as_double(((unsigned long long)r.w << 32) | r.z);
}
__device__ __forceinline__ void tstore(double* p, double v, double tag) {
  u32x4 d = pack2(v, tag);
  asm volatile("global_store_dwordx4 %0, %1, off sc0 sc1"
               :: "v"(p), "v"(d) : "memory");
}
__device__ __forceinline__ u32x4 tload1(const double* p) {
  u32x4 r;
  asm volatile("global_load_dwordx4 %0, %1, off sc0 sc1\n\t"
               "s_waitcnt vmcnt(0)"
               : "=&v"(r) : "v"(p) : "memory");
  return r;
}
__device__ __forceinline__ void tload4(const double* p, u32x4& a, u32x4& b,
                                       u32x4& c, u32x4& d) {
  asm volatile("global_load_dwordx4 %0, %4, off sc0 sc1\n\t"
               "global_load_dwordx4 %1, %4, off offset:16 sc0 sc1\n\t"
               "global_load_dwordx4 %2, %4, off offset:32 sc0 sc1\n\t"
               "global_load_dwordx4 %3, %4, off offset:48 sc0 sc1\n\t"
               "s_waitcnt vmcnt(0)"
               : "=&v"(a), "=&v"(b), "=&v"(c), "=&v"(d)
               : "v"(p) : "memory");
}
__device__ __forceinline__ void poll4(const double* p, double want, double* dst) {
  u32x4 a, b, c, d;
  int guard = 0;
  for (;;) {
    tload4(p, a, b, c, d);
    if (tag_of(a) == want && tag_of(b) == want &&
        tag_of(c) == want && tag_of(d) == want) break;
    __builtin_amdgcn_s_sleep(1);
    if (++guard > (1 << 13)) break;   // fail-safe
  }
  dst[0] = val_of(a); dst[1] = val_of(b); dst[2] = val_of(c); dst[3] = val_of(d);
}
__device__ __forceinline__ double poll1(const double* p, double want) {
  int guard = 0;
  for (;;) {
    u32x4 r = tload1(p);
    if (tag_of(r) == want) return val_of(r);
    __builtin_amdgcn_s_sleep(1);
    if (++guard > (1 << 13)) return val_of(r);   // fail-safe
  }
}

// ---------------- tiny prep kernels ----------------
__global__ void gather_emb_kernel(const int* __restrict__ target,
                                  const float* __restrict__ emb_dec,
                                  float* __restrict__ emb) {
  int t = blockIdx.x;
  int tok = (t == 0) ? 1 : target[t - 1];          // SOS=1, teacher forcing
  const float4* s = (const float4*)(emb_dec + (size_t)tok * H_DIM);
  float4* d = (float4*)(emb + (size_t)t * H_DIM);
  d[threadIdx.x] = s[threadIdx.x];
}

// init tagged buffers: enc h parity-0 = {0, tag 0}; parity-1 / s / comb = tag -1
__global__ void init_tags_kernel(double* __restrict__ hT,
                                 double* __restrict__ sD,
                                 double* __restrict__ cD) {
  int tid = threadIdx.x;
  for (int i = tid; i < H_DIM; i += 256) {
    hT[2 * i] = 0.0;                hT[2 * i + 1] = 0.0;
    hT[2 * (H_DIM + i)] = 0.0;      hT[2 * (H_DIM + i) + 1] = -1.0;
    cD[2 * i] = 0.0;                cD[2 * i + 1] = -1.0;
  }
  if (tid < 256) { sD[2 * tid] = 0.0; sD[2 * tid + 1] = -1.0; }
}

__global__ void cvt_bf16_kernel(const double* __restrict__ src,
                                unsigned short* __restrict__ dst) {
  int i = blockIdx.x * blockDim.x + threadIdx.x;   // one f64x4 each, 65536 total
  f64x4 v = ((const f64x4*)src)[i];
  ushort4 o;
  o.x = f2bf((float)v.x); o.y = f2bf((float)v.y);
  o.z = f2bf((float)v.z); o.w = f2bf((float)v.w);
  *(ushort4*)&dst[i * 4] = o;
}

// ---------------- generic f64-accum GEMM: C[m,n] = bias[n] + dot(A[m,:],B[n,:]) --
template <typename TA, typename TB>
__global__ __launch_bounds__(256) void gemm_nt_f64acc(
    const TA* __restrict__ A, int lda,
    const TB* __restrict__ B, int ldb,
    const float* __restrict__ bias,
    double* __restrict__ C, int ldc, int K) {
  __shared__ double As[32][65];
  __shared__ double Bs[32][65];
  const int tid = threadIdx.x;
  const int tx = tid & 15, ty = tid >> 4;
  const int m0 = blockIdx.y * 64, n0 = blockIdx.x * 64;
  double acc[4][4];
#pragma unroll
  for (int i = 0; i < 4; ++i)
#pragma unroll
    for (int j = 0; j < 4; ++j) acc[i][j] = 0.0;

  for (int k0 = 0; k0 < K; k0 += 32) {
#pragma unroll
    for (int q = 0; q < 8; ++q) {
      int idx = q * 256 + tid;          // 0..2047
      int row = idx >> 5;               // 0..63
      int col = idx & 31;               // 0..31
      As[col][row] = (double)A[(size_t)(m0 + row) * lda + k0 + col];
      Bs[col][row] = (double)B[(size_t)(n0 + row) * ldb + k0 + col];
    }
    __syncthreads();
#pragma unroll
    for (int kk = 0; kk < 32; ++kk) {
      double a[4], b[4];
#pragma unroll
      for (int i = 0; i < 4; ++i) a[i] = As[kk][ty * 4 + i];
#pragma unroll
      for (int j = 0; j < 4; ++j) b[j] = Bs[kk][tx * 4 + j];
#pragma unroll
      for (int i = 0; i < 4; ++i)
#pragma unroll
        for (int j = 0; j < 4; ++j) acc[i][j] += a[i] * b[j];
    }
    __syncthreads();
  }
#pragma unroll
  for (int j = 0; j < 4; ++j) {
    double bj = bias ? (double)bias[n0 + tx * 4 + j] : 0.0;
#pragma unroll
    for (int i = 0; i < 4; ++i)
      C[(size_t)(m0 + ty * 4 + i) * ldc + n0 + tx * 4 + j] = acc[i][j] + bj;
  }
}

// ---------------- encoder: 256 GRU steps, tagged dataflow + weight prefetch -----
// Weight rows are loaded into REGISTERS before the h-poll (source order keeps
// the loads above the poll asm) so L2/IC streaming overlaps the hop wait.
__global__ __launch_bounds__(256) void enc_kernel(
    const double* __restrict__ gxe,     // [256][3072] input-side gates (incl bih)
    const float* __restrict__ Whh,      // [3072][1024]
    const float* __restrict__ bhh,      // [3072]
    double* __restrict__ hT,            // [2][1024] tagged (2 doubles/elem)
    double* __restrict__ enc_outs) {    // [256][1024]
  __shared__ __align__(32) double hs[H_DIM];
  const int tid = threadIdx.x;
  const int lane = tid & 63, wave = tid >> 6;
  const int gwave = blockIdx.x * 4 + wave;   // 0..511

  for (int t = 0; t < T_LEN; ++t) {
    // ---- prefetch: Whh rows (regs) + gx scalars, BEFORE the h poll ----
    float4 wpre[2][3][4];
    double gxp[2][3], bhp[2][3];
#pragma unroll
    for (int jj = 0; jj < 2; ++jj) {
      int j = gwave * 2 + jj;
#pragma unroll
      for (int i = 0; i < 4; ++i) {
        int k = lane + 64 * i;
        wpre[jj][0][i] = ((const float4*)(Whh + (size_t)j * H_DIM))[k];
        wpre[jj][1][i] = ((const float4*)(Whh + (size_t)(j + 1024) * H_DIM))[k];
        wpre[jj][2][i] = ((const float4*)(Whh + (size_t)(j + 2048) * H_DIM))[k];
      }
      if (lane == 0) {
        const double* gx = gxe + (size_t)t * G3;
        gxp[jj][0] = gx[j]; gxp[jj][1] = gx[1024 + j]; gxp[jj][2] = gx[2048 + j];
        bhp[jj][0] = (double)bhh[j];
        bhp[jj][1] = (double)bhh[1024 + j];
        bhp[jj][2] = (double)bhh[2048 + j];
      }
    }

    poll4(&hT[2 * ((size_t)(t & 1) * H_DIM + tid * 4)], (double)t, &hs[tid * 4]);
    __syncthreads();

#pragma unroll
    for (int jj = 0; jj < 2; ++jj) {
      int j = gwave * 2 + jj;   // 0..1023
      const f64x4* h4 = (const f64x4*)hs;
      double ar = 0.0, az = 0.0, an = 0.0;
#pragma unroll
      for (int i = 0; i < 4; ++i) {
        int k = lane + 64 * i;
        f64x4 hv = h4[k];
        float4 r4 = wpre[jj][0][i], z4 = wpre[jj][1][i], n4 = wpre[jj][2][i];
        ar += hv.x * (double)r4.x + hv.y * (double)r4.y + hv.z * (double)r4.z + hv.w * (double)r4.w;
        az += hv.x * (double)z4.x + hv.y * (double)z4.y + hv.z * (double)z4.z + hv.w * (double)z4.w;
        an += hv.x * (double)n4.x + hv.y * (double)n4.y + hv.z * (double)n4.z + hv.w * (double)n4.w;
      }
      ar = wred_sum_d(ar); az = wred_sum_d(az); an = wred_sum_d(an);
      if (lane == 0) {
        double r = sigm_d(gxp[jj][0] + ar + bhp[jj][0]);
        double z = sigm_d(gxp[jj][1] + az + bhp[jj][1]);
        double n = tanh(gxp[jj][2] + r * (an + bhp[jj][2]));
        double hnew = (1.0 - z) * n + z * hs[j];
        tstore(&hT[2 * ((size_t)((t + 1) & 1) * H_DIM + j)], hnew, (double)(t + 1));
        enc_outs[(size_t)t * H_DIM + j] = hnew;   // post-kernel consumer
      }
    }
    __syncthreads();   // protect hs before next step's poll-fill
  }
}

// ---------------- decoder: 256 steps, 3 dataflow hops/step + prefetch -----------
// Same race-freedom argument as r9 (dependency cycle: h(t+1) needs comb(t) from
// all blocks, which needs s(t), which needs h(t) reads -> no overwrite races).
__global__ __launch_bounds__(256) void dec_kernel(
    const double* __restrict__ s_emb,   // [256][256]  emb@attnW_e.T + attn_b
    const double* __restrict__ cp,      // [256][1024] emb@combW_e.T + comb_b
    const double* __restrict__ M1T,     // [1024][256] combW_c @ enc_outs.T
    const float* __restrict__ attn_W,   // [256][2048]
    const float* __restrict__ Wih,      // dec [3072][1024]
    const float* __restrict__ Whh,      // dec [3072][1024]
    const float* __restrict__ bih,      // [3072]
    const float* __restrict__ bhh,      // [3072]
    double* __restrict__ hD,            // [1024] tagged (tag 256+t -> 257+t)
    double* __restrict__ sD,            // [256] tagged (tag t+1)
    double* __restrict__ cD,            // [1024] tagged (tag t+1)
    double* __restrict__ h_dec) {       // [256][1024]
  __shared__ __align__(32) double hs[H_DIM];
  __shared__ __align__(32) double cs[H_DIM];
  __shared__ __align__(32) double aw[T_LEN];
  __shared__ double rmax[4], rsum[4];
  __shared__ double whh_p[4][2][3];   // per-wave Whh·h partials (+bhh folded)
  const int tid = threadIdx.x;
  const int lane = tid & 63, wave = tid >> 6;
  const int gwave = blockIdx.x * 4 + wave;   // 0..511

  for (int t = 0; t < T_LEN; ++t) {
    // ---- phase 1 prefetch (attn_W row slice, Whh rows, scalars) ----
    float4 apre[4];
    double sep = 0.0;
    if (wave < 2) {
      int j = blockIdx.x * 2 + wave;
#pragma unroll
      for (int i = 0; i < 4; ++i)
        apre[i] = ((const float4*)(attn_W + (size_t)j * 2048 + 1024))[lane + 64 * i];
      if (lane == 0) sep = s_emb[(size_t)t * T_LEN + j];
    }
    float4 wpre[2][3][4];
    double bhp[2][3];
#pragma unroll
    for (int jj = 0; jj < 2; ++jj) {
      int j = gwave * 2 + jj;
#pragma unroll
      for (int i = 0; i < 4; ++i) {
        int k = lane + 64 * i;
        wpre[jj][0][i] = ((const float4*)(Whh + (size_t)j * H_DIM))[k];
        wpre[jj][1][i] = ((const float4*)(Whh + (size_t)(j + 1024) * H_DIM))[k];
        wpre[jj][2][i] = ((const float4*)(Whh + (size_t)(j + 2048) * H_DIM))[k];
      }
      if (lane == 0) {
        bhp[jj][0] = (double)bhh[j];
        bhp[jj][1] = (double)bhh[1024 + j];
        bhp[jj][2] = (double)bhh[2048 + j];
      }
    }

    // ---- phase 1: global h poll; s-dot FIRST (critical path); Whh dots ----
    poll4(&hD[2 * (tid * 4)], (double)(256 + t), &hs[tid * 4]);
    __syncthreads();

    if (wave < 2) {
      int j = blockIdx.x * 2 + wave;
      const f64x4* h4 = (const f64x4*)hs;
      double acc = 0.0;
#pragma unroll
      for (int i = 0; i < 4; ++i) {
        int k = lane + 64 * i;
        float4 wv = apre[i]; f64x4 hv = h4[k];
        acc += (double)wv.x * hv.x + (double)wv.y * hv.y +
               (double)wv.z * hv.z + (double)wv.w * hv.w;
      }
      acc = wred_sum_d(acc);
      if (lane == 0) tstore(&sD[2 * j], sep + acc, (double)(t + 1));
    }
#pragma unroll
    for (int jj = 0; jj < 2; ++jj) {
      const f64x4* h4 = (const f64x4*)hs;
      double ahr = 0.0, ahz = 0.0, ahn = 0.0;
#pragma unroll
      for (int i = 0; i < 4; ++i) {
        int k = lane + 64 * i;
        f64x4 hv = h4[k];
        float4 t3 = wpre[jj][0][i], t4 = wpre[jj][1][i], t5 = wpre[jj][2][i];
        ahr += hv.x * (double)t3.x + hv.y * (double)t3.y + hv.z * (double)t3.z + hv.w * (double)t3.w;
        ahz += hv.x * (double)t4.x + hv.y * (double)t4.y + hv.z * (double)t4.z + hv.w * (double)t4.w;
        ahn += hv.x * (double)t5.x + hv.y * (double)t5.y + hv.z * (double)t5.z + hv.w * (double)t5.w;
      }
      ahr = wred_sum_d(ahr); ahz = wred_sum_d(ahz); ahn = wred_sum_d(ahn);
      if (lane == 0) {
        whh_p[wave][jj][0] = ahr + bhp[jj][0];
        whh_p[wave][jj][1] = ahz + bhp[jj][1];
        whh_p[wave][jj][2] = ahn + bhp[jj][2];
      }
    }

    // ---- phase 2 prefetch (M1T row slices + cp scalars) ----
    f64x4 mpre[2];
    double cpp[2];
#pragma unroll
    for (int jj = 0; jj < 2; ++jj) {
      int j = gwave * 2 + jj;
      mpre[jj] = ((const f64x4*)(M1T + (size_t)j * T_LEN))[lane];
      if (lane == 0) cpp[jj] = cp[(size_t)t * H_DIM + j];
    }

    // ---- phase 2: poll s; redundant softmax; comb = relu(cp + aw@M1T) ----
    {
      double sv = poll1(&sD[2 * tid], (double)(t + 1));   // tid < 256 exactly
      double m = wred_max_d(sv);
      if (lane == 0) rmax[wave] = m;
      __syncthreads();
      double mx = fmax(fmax(rmax[0], rmax[1]), fmax(rmax[2], rmax[3]));
      double e = exp(sv - mx);
      double ssum = wred_sum_d(e);
      if (lane == 0) rsum[wave] = ssum;
      __syncthreads();
      double inv = 1.0 / (rsum[0] + rsum[1] + rsum[2] + rsum[3]);
      aw[tid] = e * inv;
      __syncthreads();
    }
#pragma unroll
    for (int jj = 0; jj < 2; ++jj) {
      int j = gwave * 2 + jj;
      f64x4 mv = mpre[jj];
      f64x4 av = ((const f64x4*)aw)[lane];
      double acc = mv.x * av.x + mv.y * av.y + mv.z * av.z + mv.w * av.w;
      acc = wred_sum_d(acc);
      if (lane == 0) {
        double v = cpp[jj] + acc;
        tstore(&cD[2 * j], v > 0.0 ? v : 0.0, (double)(t + 1));
      }
    }

    // ---- phase 3 prefetch (Wih rows + bih scalars) ----
    float4 ipre[2][3][4];
    double bip[2][3];
#pragma unroll
    for (int jj = 0; jj < 2; ++jj) {
      int j = gwave * 2 + jj;
#pragma unroll
      for (int i = 0; i < 4; ++i) {
        int k = lane + 64 * i;
        ipre[jj][0][i] = ((const float4*)(Wih + (size_t)j * H_DIM))[k];
        ipre[jj][1][i] = ((const float4*)(Wih + (size_t)(j + 1024) * H_DIM))[k];
        ipre[jj][2][i] = ((const float4*)(Wih + (size_t)(j + 2048) * H_DIM))[k];
      }
      if (lane == 0) {
        bip[jj][0] = (double)bih[j];
        bip[jj][1] = (double)bih[1024 + j];
        bip[jj][2] = (double)bih[2048 + j];
      }
    }

    // ---- phase 3: poll comb; Wih dots + gates; publish h ----
    poll4(&cD[2 * (tid * 4)], (double)(t + 1), &cs[tid * 4]);
    __syncthreads();
#pragma unroll
    for (int jj = 0; jj < 2; ++jj) {
      int j = gwave * 2 + jj;
      const f64x4* c4 = (const f64x4*)cs;
      double air = 0.0, aiz = 0.0, ain = 0.0;
#pragma unroll
      for (int i = 0; i < 4; ++i) {
        int k = lane + 64 * i;
        f64x4 cv = c4[k];
        float4 t0 = ipre[jj][0][i], t1 = ipre[jj][1][i], t2 = ipre[jj][2][i];
        air += cv.x * (double)t0.x + cv.y * (double)t0.y + cv.z * (double)t0.z + cv.w * (double)t0.w;
        aiz += cv.x * (double)t1.x + cv.y * (double)t1.y + cv.z * (double)t1.z + cv.w * (double)t1.w;
        ain += cv.x * (double)t2.x + cv.y * (double)t2.y + cv.z * (double)t2.z + cv.w * (double)t2.w;
      }
      air = wred_sum_d(air); aiz = wred_sum_d(aiz); ain = wred_sum_d(ain);
      if (lane == 0) {
        double r = sigm_d(air + bip[jj][0] + whh_p[wave][jj][0]);
        double z = sigm_d(aiz + bip[jj][1] + whh_p[wave][jj][1]);
        double n = tanh(ain + bip[jj][2] + r * whh_p[wave][jj][2]);
        double hnew = (1.0 - z) * n + z * hs[j];
        tstore(&hD[2 * j], hnew, (double)(257 + t));
        h_dec[(size_t)t * H_DIM + j] = hnew;   // post-kernel consumer
      }
    }
    __syncthreads();   // protect hs/cs/aw/whh_p before next step's poll-fill
  }
}

// ---------------- output GEMM: C[256,50257] = Abf @ out_W.T + out_b (bf16 MFMA) --
__global__ __launch_bounds__(256) void out_gemm_kernel(
    const unsigned short* __restrict__ Abf,  // [256][1024] bf16
    const float* __restrict__ Bw,            // [50257][1024] f32 (converted inline)
    const float* __restrict__ bias,          // [50257]
    float* __restrict__ C) {                 // [256][50257]
  __shared__ unsigned short As[256][40];
  __shared__ unsigned short Bs[64][40];
  const int tid = threadIdx.x;
  const int lane = tid & 63, wave = tid >> 6;
  const int n0 = blockIdx.x * 64;
  f32x4 acc[4][4];
#pragma unroll
  for (int i = 0; i < 4; ++i)
#pragma unroll
    for (int j = 0; j < 4; ++j) acc[i][j] = (f32x4){0.f, 0.f, 0.f, 0.f};

  for (int k0 = 0; k0 < 1024; k0 += 32) {
#pragma unroll
    for (int q = 0; q < 4; ++q) {               // stage A: [256][32] bf16
      int idx = (tid + q * 256) * 8;
      int m = idx >> 5, k = idx & 31;
      uint4 v = *(const uint4*)&Abf[(size_t)m * H_DIM + k0 + k];
      *(uint4*)&As[m][k] = v;
    }
#pragma unroll
    for (int q = 0; q < 2; ++q) {               // stage B: [64][32] f32 -> bf16
      int idx = (tid + q * 256) * 4;
      int r = idx >> 5, c = idx & 31;
      int n = n0 + r;
      float4 v = make_float4(0.f, 0.f, 0.f, 0.f);
      if (n < V_DIM) v = *(const float4*)&Bw[(size_t)n * H_DIM + k0 + c];
      ushort4 o;
      o.x = f2bf(v.x); o.y = f2bf(v.y); o.z = f2bf(v.z); o.w = f2bf(v.w);
      *(ushort4*)&Bs[r][c] = o;
    }
    __syncthreads();
    bf16x8 a[4], b[4];
#pragma unroll
    for (int i = 0; i < 4; ++i)
      a[i] = *(const bf16x8*)&As[wave * 64 + i * 16 + (lane & 15)][(lane >> 4) * 8];
#pragma unroll
    for (int j = 0; j < 4; ++j)
      b[j] = *(const bf16x8*)&Bs[j * 16 + (lane & 15)][(lane >> 4) * 8];
#pragma unroll
    for (int i = 0; i < 4; ++i)
#pragma unroll
      for (int j = 0; j < 4; ++j)
        acc[i][j] = __builtin_amdgcn_mfma_f32_16x16x32_bf16(a[i], b[j], acc[i][j], 0, 0, 0);
    __syncthreads();
  }
  const int col = lane & 15, rgrp = lane >> 4;
#pragma unroll
  for (int j = 0; j < 4; ++j) {
    int n = n0 + j * 16 + col;
    if (n >= V_DIM) continue;
    float bv = bias[n];
#pragma unroll
    for (int i = 0; i < 4; ++i) {
      int mbase = wave * 64 + i * 16 + rgrp * 4;
#pragma unroll
      for (int r = 0; r < 4; ++r)
        C[(size_t)(mbase + r) * V_DIM + n] = acc[i][j][r] + bv;
    }
  }
}

// ---------------- in-place row log_softmax over V (f64 sum) ----------------
__global__ __launch_bounds__(1024) void logsoftmax_kernel(float* __restrict__ x) {
  const int row = blockIdx.x;
  float* p = x + (size_t)row * V_DIM;
  const int tid = threadIdx.x;
  __shared__ float redf[16];
  __shared__ double redd[16];
  float mx = -3.4e38f;
  for (int i = tid; i < V_DIM; i += 1024) mx = fmaxf(mx, p[i]);
#pragma unroll
  for (int off = 32; off > 0; off >>= 1) mx = fmaxf(mx, __shfl_down(mx, off));
  if ((tid & 63) == 0) redf[tid >> 6] = mx;
  __syncthreads();
  mx = redf[0];
#pragma unroll
  for (int i = 1; i < 16; ++i) mx = fmaxf(mx, redf[i]);
  __syncthreads();
  double s = 0.0;
  for (int i = tid; i < V_DIM; i += 1024) s += exp((double)p[i] - (double)mx);
  s = wred_sum_d(s);
  if ((tid & 63) == 0) redd[tid >> 6] = s;
  __syncthreads();
  s = 0.0;
#pragma unroll
  for (int i = 0; i < 16; ++i) s += redd[i];
  double lse = (double)mx + log(s);
  for (int i = tid; i < V_DIM; i += 1024) p[i] = (float)((double)p[i] - lse);
}

// ---------------- launch ----------------
extern "C" void kernel_launch(void* const* d_in, const int* in_sizes, int n_in,
                              void* d_out, int out_size, void* d_ws, size_t ws_size,
                              hipStream_t stream) {
  const float* input_seq = (const float*)d_in[0];
  const int*   target    = (const int*)d_in[1];
  const float* emb_dec   = (const float*)d_in[2];
  const float* enc_Wih   = (const float*)d_in[3];
  const float* enc_Whh   = (const float*)d_in[4];
  const float* enc_bih   = (const float*)d_in[5];
  const float* enc_bhh   = (const float*)d_in[6];
  const float* attn_W    = (const float*)d_in[7];
  const float* attn_b    = (const float*)d_in[8];
  const float* comb_W    = (const float*)d_in[9];
  const float* comb_b    = (const float*)d_in[10];
  const float* dec_Wih   = (const float*)d_in[11];
  const float* dec_Whh   = (const float*)d_in[12];
  const float* dec_bih   = (const float*)d_in[13];
  const float* dec_bhh   = (const float*)d_in[14];
  const float* out_W     = (const float*)d_in[15];
  const float* out_b     = (const float*)d_in[16];
  float* out = (float*)d_out;

  // f64 scratch that dies before out_gemm lives inside d_out (51.5 MB total).
  double* od = (double*)d_out;
  double* gxe      = od;                     // 256*3072  (dead after enc)
  double* s_emb    = gxe + 256 * 3072;       // 256*256   (dead after dec)
  double* cp       = s_emb + 256 * 256;      // 256*1024  (dead after dec)
  double* enc_outs = cp + 256 * 1024;        // 256*1024  (dead after M1T)
  double* M1T      = enc_outs + 256 * 1024;  // 1024*256  (dead after dec)
  double* h_dec    = M1T + 1024 * 256;       // 256*1024  (dead after cvt)
  // persistent-through-out_gemm scratch in d_ws (tagged elems = 2 doubles each)
  double* hT = (double*)d_ws;                // [2][1024] tagged h (enc dbuf; dec uses [0])
  double* sD = hT + 2 * 2 * H_DIM;           // [256] tagged s
  double* cD = sD + 2 * 256;                 // [1024] tagged comb
  float*  emb = (float*)(cD + 2 * H_DIM);                        // 256*1024 f32
  unsigned short* hdec_bf = (unsigned short*)(emb + 256 * 1024); // 256*1024 bf16

  // prep (re-inits all tags -> deterministic replays)
  gather_emb_kernel<<<256, 256, 0, stream>>>(target, emb_dec, emb);
  init_tags_kernel<<<1, 256, 0, stream>>>(hT, sD, cD);

  // f64-accum pre-GEMMs
  gemm_nt_f64acc<float, float><<<dim3(48, 4), 256, 0, stream>>>(
      input_seq, 1024, enc_Wih, 1024, enc_bih, gxe, 3072, 1024);
  gemm_nt_f64acc<float, float><<<dim3(4, 4), 256, 0, stream>>>(
      emb, 1024, attn_W, 2048, attn_b, s_emb, 256, 1024);
  gemm_nt_f64acc<float, float><<<dim3(16, 4), 256, 0, stream>>>(
      emb, 1024, comb_W, 2048, comb_b, cp, 1024, 1024);

  // encoder recurrence (tagged dataflow; leaves h tag=256 in hT[0..1023])
  enc_kernel<<<NBLK, 256, 0, stream>>>(gxe, enc_Whh, enc_bhh, hT, enc_outs);

  // M1T = comb_W[:, H:] @ enc_outs.T -> [1024][256]
  gemm_nt_f64acc<float, double><<<dim3(4, 16), 256, 0, stream>>>(
      comb_W + 1024, 2048, enc_outs, 1024, nullptr, M1T, 256, 1024);

  // decoder recurrence (tagged dataflow, no barriers)
  dec_kernel<<<NBLK, 256, 0, stream>>>(s_emb, cp, M1T, attn_W, dec_Wih, dec_Whh,
                                       dec_bih, dec_bhh, hT, sD, cD, h_dec);

  // output projection + log_softmax (overwrites all of d_out)
  cvt_bf16_kernel<<<256, 256, 0, stream>>>(h_dec, hdec_bf);
  out_gemm_kernel<<<786, 256, 0, stream>>>(hdec_bf, out_W, out_b, out);
  logsoftmax_kernel<<<256, 1024, 0, stream>>>(out);
}